// Round 4
// baseline (244.793 us; speedup 1.0000x reference)
//
#include <hip/hip_runtime.h>
#include <hip/hip_bf16.h>

// SupplyChainGNN: 3-layer GCN, N=50000, E=800000, H=64.
// Round 15: kill the gather's serial idx chain. Block's CSR slice (contiguous,
// dst-sorted) is staged into LDS once (coalesced); per-node idx fetches become
// ~100cyc broadcast ds_reads instead of global loads, and the scattered-load
// pipeline deepens 8 -> 16 outstanding per half-wave. Remainder is clamped-
// masked (dup loads MSHR-merge, no extra fabric traffic). Blocks with >ECAP
// edges (never happens for this data: 1024+-32) fall back to the global path.
// Conv/heads unchanged from R14 (wave-uniform scalar weight loads).

#define HDIM 64
#define PB 128          // blocks in hist/bin passes
#define NPB 256         // nodes per bucket
#define NPB_SHIFT 8
#define ECAP 2048       // staged edges per 64-node block (mean 1024, sigma 32)

__device__ inline unsigned bfpack(float lo, float hi) {
    unsigned ul = __float_as_uint(lo), uh = __float_as_uint(hi);
    ul += 0x7fffu + ((ul >> 16) & 1u);
    uh += 0x7fffu + ((uh >> 16) & 1u);
    return (ul >> 16) | (uh & 0xffff0000u);
}

__device__ inline float2 bfunpack(unsigned u) {
    float2 r;
    r.x = __uint_as_float(u << 16);
    r.y = __uint_as_float(u & 0xffff0000u);
    return r;
}

// Pass 1: histT[k*PB + p] = #edges of block p with dst in bucket k  (NB<=256)
__global__ __launch_bounds__(256) void hist_pass(const int* __restrict__ dst,
                                                 unsigned* __restrict__ histT,
                                                 int E, int NB) {
    __shared__ unsigned h[256];
    int t = threadIdx.x, p = blockIdx.x;
    h[t] = 0u;
    __syncthreads();
    int chunk = (E + PB - 1) / PB;
    int lo = p * chunk, hi = min(lo + chunk, E);
    for (int e = lo + t; e < hi; e += 256)
        atomicAdd(&h[dst[e] >> NPB_SHIFT], 1u);
    __syncthreads();
    if (t < NB) histT[t * PB + p] = h[t];
}

// Pass 2: per-bucket exclusive scan of its PB per-block counts (in place);
// bucket total -> btot[k].
__global__ __launch_bounds__(128) void scan_bucket(unsigned* __restrict__ histT,
                                                   unsigned* __restrict__ btot) {
    __shared__ unsigned s[PB];
    int t = threadIdx.x, k = blockIdx.x;
    unsigned v = histT[k * PB + t];
    s[t] = v;
    __syncthreads();
#pragma unroll
    for (int off = 1; off < PB; off <<= 1) {
        unsigned u = (t >= off) ? s[t - off] : 0u;
        __syncthreads();
        s[t] += u;
        __syncthreads();
    }
    histT[k * PB + t] = s[t] - v;
    if (t == PB - 1) btot[k] = s[t];
}

// Pass 3: scatter packed (dst_local<<16)|src into bucket-grouped ebuf.
__global__ __launch_bounds__(256) void bin_pass(const int* __restrict__ ei,
                                                const unsigned* __restrict__ histT,
                                                const unsigned* __restrict__ btot,
                                                unsigned* __restrict__ ebuf,
                                                int E, int NB) {
    __shared__ unsigned bb[256];
    __shared__ unsigned cur[256];
    int t = threadIdx.x, p = blockIdx.x;
    unsigned bv = (t < NB) ? btot[t] : 0u;
    bb[t] = bv;
    __syncthreads();
#pragma unroll
    for (int off = 1; off < 256; off <<= 1) {
        unsigned u = (t >= off) ? bb[t - off] : 0u;
        __syncthreads();
        bb[t] += u;
        __syncthreads();
    }
    if (t < NB) cur[t] = histT[t * PB + p] + (bb[t] - bv);
    __syncthreads();
    int chunk = (E + PB - 1) / PB;
    int lo = p * chunk, hi = min(lo + chunk, E);
    for (int e = lo + t; e < hi; e += 256) {
        unsigned sN = (unsigned)ei[e];
        unsigned dN = (unsigned)ei[E + e];
        unsigned pos = atomicAdd(&cur[dN >> NPB_SHIFT], 1u);
        ebuf[pos] = ((dN & (NPB - 1u)) << 16) | sN;
    }
}

// Pass 4: one block per bucket -> row_ptr, dinv, csr_src.
__global__ __launch_bounds__(256) void csr_pass(const unsigned* __restrict__ ebuf,
                                                const unsigned* __restrict__ btot,
                                                unsigned* __restrict__ row_ptr,
                                                float* __restrict__ dinv,
                                                int* __restrict__ csr_src,
                                                int N, int E, int NB) {
    __shared__ unsigned bb[256];
    __shared__ unsigned cntL[NPB];
    __shared__ unsigned sc[NPB];
    __shared__ unsigned cur[NPB];
    int t = threadIdx.x, k = blockIdx.x;
    unsigned bv = (t < NB) ? btot[t] : 0u;
    bb[t] = bv;
    __syncthreads();
#pragma unroll
    for (int off = 1; off < 256; off <<= 1) {
        unsigned u = (t >= off) ? bb[t - off] : 0u;
        __syncthreads();
        bb[t] += u;
        __syncthreads();
    }
    unsigned e1 = bb[k];
    unsigned e0 = e1 - btot[k];
    int nbase = k << NPB_SHIFT;
    cntL[t] = 0u;
    __syncthreads();
    for (unsigned e = e0 + t; e < e1; e += 256)
        atomicAdd(&cntL[ebuf[e] >> 16], 1u);
    __syncthreads();
    unsigned v = cntL[t];
    sc[t] = v;
    __syncthreads();
#pragma unroll
    for (int off = 1; off < NPB; off <<= 1) {
        unsigned u = (t >= off) ? sc[t - off] : 0u;
        __syncthreads();
        sc[t] += u;
        __syncthreads();
    }
    unsigned pos0 = e0 + sc[t] - v;
    cur[t] = pos0;
    int node = nbase + t;
    if (node < N) {
        row_ptr[node] = pos0;
        dinv[node] = rsqrtf((float)(v + 1u));
    }
    if (k == NB - 1 && t == 0) row_ptr[N] = (unsigned)E;
    __syncthreads();
    for (unsigned e = e0 + t; e < e1; e += 256) {
        unsigned ed = ebuf[e];
        unsigned pos = atomicAdd(&cur[ed >> 16], 1u);
        csr_src[pos] = (int)(ed & 0xffffu);
    }
}

// hn[i] = bf16( dinv[i] * relu(x@W+b) ); thread per feature-pair.
__global__ __launch_bounds__(256) void encoder(const float* __restrict__ x,
                                               const float* __restrict__ W,
                                               const float* __restrict__ b,
                                               const float* __restrict__ dinv,
                                               unsigned* __restrict__ hn, int N) {
    int t = blockIdx.x * 256 + threadIdx.x;
    int i = t >> 5, jp = t & 31;
    if (i >= N) return;
    int j0 = 2 * jp;
    float a0 = b[j0], a1 = b[j0 + 1];
#pragma unroll
    for (int k = 0; k < 5; k++) {
        float xv = x[i * 5 + k];
        a0 = fmaf(xv, W[k * 64 + j0], a0);
        a1 = fmaf(xv, W[k * 64 + j0 + 1], a1);
    }
    float di = dinv[i];
    hn[t] = bfpack(di * fmaxf(a0, 0.0f), di * fmaxf(a1, 0.0f));
}

// LDS-idx gather: idx from broadcast ds_reads (off the global-latency chain),
// 16 scattered loads in flight per half-wave.
__device__ inline float2 gather_row_lds(const int* __restrict__ eL, int r0, unsigned cnt,
                                        const unsigned* __restrict__ hn, int i, int fl) {
    float2 a0 = bfunpack(hn[(size_t)i * 32 + fl]);  // self term
    float2 a1 = {0.f, 0.f}, a2 = a1, a3 = a1, a4 = a1, a5 = a1, a6 = a1, a7 = a1;
    unsigned u = 0;
    if (cnt >= 16) {
        int s0 = eL[r0+0],  s1 = eL[r0+1],  s2 = eL[r0+2],  s3 = eL[r0+3];
        int s4 = eL[r0+4],  s5 = eL[r0+5],  s6 = eL[r0+6],  s7 = eL[r0+7];
        int s8 = eL[r0+8],  s9 = eL[r0+9],  s10 = eL[r0+10], s11 = eL[r0+11];
        int s12 = eL[r0+12], s13 = eL[r0+13], s14 = eL[r0+14], s15 = eL[r0+15];
        while (true) {
            unsigned v0 = hn[(size_t)s0 * 32 + fl];
            unsigned v1 = hn[(size_t)s1 * 32 + fl];
            unsigned v2 = hn[(size_t)s2 * 32 + fl];
            unsigned v3 = hn[(size_t)s3 * 32 + fl];
            unsigned v4 = hn[(size_t)s4 * 32 + fl];
            unsigned v5 = hn[(size_t)s5 * 32 + fl];
            unsigned v6 = hn[(size_t)s6 * 32 + fl];
            unsigned v7 = hn[(size_t)s7 * 32 + fl];
            unsigned v8 = hn[(size_t)s8 * 32 + fl];
            unsigned v9 = hn[(size_t)s9 * 32 + fl];
            unsigned v10 = hn[(size_t)s10 * 32 + fl];
            unsigned v11 = hn[(size_t)s11 * 32 + fl];
            unsigned v12 = hn[(size_t)s12 * 32 + fl];
            unsigned v13 = hn[(size_t)s13 * 32 + fl];
            unsigned v14 = hn[(size_t)s14 * 32 + fl];
            unsigned v15 = hn[(size_t)s15 * 32 + fl];
            unsigned un = u + 16;
            bool more = (un + 16 <= cnt);
            if (more) {
                int rb = r0 + (int)un;
                s0 = eL[rb+0];  s1 = eL[rb+1];  s2 = eL[rb+2];  s3 = eL[rb+3];
                s4 = eL[rb+4];  s5 = eL[rb+5];  s6 = eL[rb+6];  s7 = eL[rb+7];
                s8 = eL[rb+8];  s9 = eL[rb+9];  s10 = eL[rb+10]; s11 = eL[rb+11];
                s12 = eL[rb+12]; s13 = eL[rb+13]; s14 = eL[rb+14]; s15 = eL[rb+15];
            }
            float2 f0 = bfunpack(v0), f1 = bfunpack(v1), f2 = bfunpack(v2), f3 = bfunpack(v3);
            float2 f4 = bfunpack(v4), f5 = bfunpack(v5), f6 = bfunpack(v6), f7 = bfunpack(v7);
            float2 f8 = bfunpack(v8), f9 = bfunpack(v9), f10 = bfunpack(v10), f11 = bfunpack(v11);
            float2 f12 = bfunpack(v12), f13 = bfunpack(v13), f14 = bfunpack(v14), f15 = bfunpack(v15);
            a0.x += f0.x;  a0.y += f0.y;   a1.x += f1.x;  a1.y += f1.y;
            a2.x += f2.x;  a2.y += f2.y;   a3.x += f3.x;  a3.y += f3.y;
            a4.x += f4.x;  a4.y += f4.y;   a5.x += f5.x;  a5.y += f5.y;
            a6.x += f6.x;  a6.y += f6.y;   a7.x += f7.x;  a7.y += f7.y;
            a0.x += f8.x;  a0.y += f8.y;   a1.x += f9.x;  a1.y += f9.y;
            a2.x += f10.x; a2.y += f10.y;  a3.x += f11.x; a3.y += f11.y;
            a4.x += f12.x; a4.y += f12.y;  a5.x += f13.x; a5.y += f13.y;
            a6.x += f14.x; a6.y += f14.y;  a7.x += f15.x; a7.y += f15.y;
            u = un;
            if (!more) break;
        }
    }
    if (u < cnt) {  // 1..15 remainder, clamped (dup loads MSHR-merge)
        unsigned last = cnt - 1;
        int t0 = eL[r0 + (int)min(u + 0u, last)];
        int t1 = eL[r0 + (int)min(u + 1u, last)];
        int t2 = eL[r0 + (int)min(u + 2u, last)];
        int t3 = eL[r0 + (int)min(u + 3u, last)];
        int t4 = eL[r0 + (int)min(u + 4u, last)];
        int t5 = eL[r0 + (int)min(u + 5u, last)];
        int t6 = eL[r0 + (int)min(u + 6u, last)];
        int t7 = eL[r0 + (int)min(u + 7u, last)];
        int t8 = eL[r0 + (int)min(u + 8u, last)];
        int t9 = eL[r0 + (int)min(u + 9u, last)];
        int t10 = eL[r0 + (int)min(u + 10u, last)];
        int t11 = eL[r0 + (int)min(u + 11u, last)];
        int t12 = eL[r0 + (int)min(u + 12u, last)];
        int t13 = eL[r0 + (int)min(u + 13u, last)];
        int t14 = eL[r0 + (int)min(u + 14u, last)];
        int t15 = eL[r0 + (int)min(u + 15u, last)];
        unsigned w0 = hn[(size_t)t0 * 32 + fl];
        unsigned w1 = hn[(size_t)t1 * 32 + fl];
        unsigned w2 = hn[(size_t)t2 * 32 + fl];
        unsigned w3 = hn[(size_t)t3 * 32 + fl];
        unsigned w4 = hn[(size_t)t4 * 32 + fl];
        unsigned w5 = hn[(size_t)t5 * 32 + fl];
        unsigned w6 = hn[(size_t)t6 * 32 + fl];
        unsigned w7 = hn[(size_t)t7 * 32 + fl];
        unsigned w8 = hn[(size_t)t8 * 32 + fl];
        unsigned w9 = hn[(size_t)t9 * 32 + fl];
        unsigned w10 = hn[(size_t)t10 * 32 + fl];
        unsigned w11 = hn[(size_t)t11 * 32 + fl];
        unsigned w12 = hn[(size_t)t12 * 32 + fl];
        unsigned w13 = hn[(size_t)t13 * 32 + fl];
        unsigned w14 = hn[(size_t)t14 * 32 + fl];
        unsigned w15 = hn[(size_t)t15 * 32 + fl];
        float2 f0 = bfunpack(w0), f1 = bfunpack(w1), f2 = bfunpack(w2), f3 = bfunpack(w3);
        float2 f4 = bfunpack(w4), f5 = bfunpack(w5), f6 = bfunpack(w6), f7 = bfunpack(w7);
        float2 f8 = bfunpack(w8), f9 = bfunpack(w9), f10 = bfunpack(w10), f11 = bfunpack(w11);
        float2 f12 = bfunpack(w12), f13 = bfunpack(w13), f14 = bfunpack(w14), f15 = bfunpack(w15);
        a0.x += f0.x;                         a0.y += f0.y;
        a1.x += (u + 1 < cnt) ? f1.x : 0.f;   a1.y += (u + 1 < cnt) ? f1.y : 0.f;
        a2.x += (u + 2 < cnt) ? f2.x : 0.f;   a2.y += (u + 2 < cnt) ? f2.y : 0.f;
        a3.x += (u + 3 < cnt) ? f3.x : 0.f;   a3.y += (u + 3 < cnt) ? f3.y : 0.f;
        a4.x += (u + 4 < cnt) ? f4.x : 0.f;   a4.y += (u + 4 < cnt) ? f4.y : 0.f;
        a5.x += (u + 5 < cnt) ? f5.x : 0.f;   a5.y += (u + 5 < cnt) ? f5.y : 0.f;
        a6.x += (u + 6 < cnt) ? f6.x : 0.f;   a6.y += (u + 6 < cnt) ? f6.y : 0.f;
        a7.x += (u + 7 < cnt) ? f7.x : 0.f;   a7.y += (u + 7 < cnt) ? f7.y : 0.f;
        a0.x += (u + 8 < cnt) ? f8.x : 0.f;   a0.y += (u + 8 < cnt) ? f8.y : 0.f;
        a1.x += (u + 9 < cnt) ? f9.x : 0.f;   a1.y += (u + 9 < cnt) ? f9.y : 0.f;
        a2.x += (u + 10 < cnt) ? f10.x : 0.f; a2.y += (u + 10 < cnt) ? f10.y : 0.f;
        a3.x += (u + 11 < cnt) ? f11.x : 0.f; a3.y += (u + 11 < cnt) ? f11.y : 0.f;
        a4.x += (u + 12 < cnt) ? f12.x : 0.f; a4.y += (u + 12 < cnt) ? f12.y : 0.f;
        a5.x += (u + 13 < cnt) ? f13.x : 0.f; a5.y += (u + 13 < cnt) ? f13.y : 0.f;
        a6.x += (u + 14 < cnt) ? f14.x : 0.f; a6.y += (u + 14 < cnt) ? f14.y : 0.f;
        a7.x += (u + 15 < cnt) ? f15.x : 0.f; a7.y += (u + 15 < cnt) ? f15.y : 0.f;
    }
    a0.x += a1.x; a0.y += a1.y;  a2.x += a3.x; a2.y += a3.y;
    a4.x += a5.x; a4.y += a5.y;  a6.x += a7.x; a6.y += a7.y;
    a0.x += a2.x; a0.y += a2.y;  a4.x += a6.x; a4.y += a6.y;
    a0.x += a4.x; a0.y += a4.y;
    return a0;
}

// Fallback (block edge list > ECAP; never for this data): R10 global-idx gather.
__device__ inline float2 gather_row(const unsigned* __restrict__ row_ptr,
                                    const int* __restrict__ csr_src,
                                    const unsigned* __restrict__ hn,
                                    int i, int fl) {
    float2 a0 = bfunpack(hn[(size_t)i * 32 + fl]);
    float2 a1 = {0.f, 0.f}, a2 = a1, a3 = a1, a4 = a1, a5 = a1, a6 = a1, a7 = a1;
    unsigned e0 = row_ptr[i];
    unsigned cnt = row_ptr[i + 1] - e0;
    const int* idx = csr_src + e0;
    unsigned u = 0;
    if (cnt >= 8) {
        int s0 = idx[0], s1 = idx[1], s2 = idx[2], s3 = idx[3];
        int s4 = idx[4], s5 = idx[5], s6 = idx[6], s7 = idx[7];
        while (true) {
            unsigned v0 = hn[(size_t)s0 * 32 + fl];
            unsigned v1 = hn[(size_t)s1 * 32 + fl];
            unsigned v2 = hn[(size_t)s2 * 32 + fl];
            unsigned v3 = hn[(size_t)s3 * 32 + fl];
            unsigned v4 = hn[(size_t)s4 * 32 + fl];
            unsigned v5 = hn[(size_t)s5 * 32 + fl];
            unsigned v6 = hn[(size_t)s6 * 32 + fl];
            unsigned v7 = hn[(size_t)s7 * 32 + fl];
            unsigned un = u + 8;
            bool more = (un + 8 <= cnt);
            if (more) {
                s0 = idx[un + 0]; s1 = idx[un + 1]; s2 = idx[un + 2]; s3 = idx[un + 3];
                s4 = idx[un + 4]; s5 = idx[un + 5]; s6 = idx[un + 6]; s7 = idx[un + 7];
            }
            float2 f0 = bfunpack(v0), f1 = bfunpack(v1), f2 = bfunpack(v2), f3 = bfunpack(v3);
            float2 f4 = bfunpack(v4), f5 = bfunpack(v5), f6 = bfunpack(v6), f7 = bfunpack(v7);
            a0.x += f0.x; a0.y += f0.y;  a1.x += f1.x; a1.y += f1.y;
            a2.x += f2.x; a2.y += f2.y;  a3.x += f3.x; a3.y += f3.y;
            a4.x += f4.x; a4.y += f4.y;  a5.x += f5.x; a5.y += f5.y;
            a6.x += f6.x; a6.y += f6.y;  a7.x += f7.x; a7.y += f7.y;
            u = un;
            if (!more) break;
        }
    }
    if (u < cnt) {
        unsigned last = cnt - 1;
        int s0 = idx[u];
        int s1 = idx[min(u + 1, last)];
        int s2 = idx[min(u + 2, last)];
        int s3 = idx[min(u + 3, last)];
        int s4 = idx[min(u + 4, last)];
        int s5 = idx[min(u + 5, last)];
        int s6 = idx[min(u + 6, last)];
        int s7 = idx[min(u + 7, last)];
        unsigned v0 = hn[(size_t)s0 * 32 + fl];
        unsigned v1 = hn[(size_t)s1 * 32 + fl];
        unsigned v2 = hn[(size_t)s2 * 32 + fl];
        unsigned v3 = hn[(size_t)s3 * 32 + fl];
        unsigned v4 = hn[(size_t)s4 * 32 + fl];
        unsigned v5 = hn[(size_t)s5 * 32 + fl];
        unsigned v6 = hn[(size_t)s6 * 32 + fl];
        unsigned v7 = hn[(size_t)s7 * 32 + fl];
        float2 f0 = bfunpack(v0), f1 = bfunpack(v1), f2 = bfunpack(v2), f3 = bfunpack(v3);
        float2 f4 = bfunpack(v4), f5 = bfunpack(v5), f6 = bfunpack(v6), f7 = bfunpack(v7);
        a0.x += f0.x;                        a0.y += f0.y;
        a1.x += (u + 1 < cnt) ? f1.x : 0.f;  a1.y += (u + 1 < cnt) ? f1.y : 0.f;
        a2.x += (u + 2 < cnt) ? f2.x : 0.f;  a2.y += (u + 2 < cnt) ? f2.y : 0.f;
        a3.x += (u + 3 < cnt) ? f3.x : 0.f;  a3.y += (u + 3 < cnt) ? f3.y : 0.f;
        a4.x += (u + 4 < cnt) ? f4.x : 0.f;  a4.y += (u + 4 < cnt) ? f4.y : 0.f;
        a5.x += (u + 5 < cnt) ? f5.x : 0.f;  a5.y += (u + 5 < cnt) ? f5.y : 0.f;
        a6.x += (u + 6 < cnt) ? f6.x : 0.f;  a6.y += (u + 6 < cnt) ? f6.y : 0.f;
        a7.x += (u + 7 < cnt) ? f7.x : 0.f;  a7.y += (u + 7 < cnt) ? f7.y : 0.f;
    }
    a0.x += a1.x; a0.y += a1.y;  a2.x += a3.x; a2.y += a3.y;
    a4.x += a5.x; a4.y += a5.y;  a6.x += a7.x; a6.y += a7.y;
    a0.x += a2.x; a0.y += a2.y;  a4.x += a6.x; a4.y += a6.y;
    a0.x += a4.x; a0.y += a4.y;
    return a0;
}

// 8 FMAs: acc0,acc1 (float4) += hk * 8-wide W row segment (wave-uniform)
#define CONV_K8(WROW, HK) do {                                                  \
    float4 wa = ((const float4*)(WROW))[0];                                     \
    float4 wb = ((const float4*)(WROW))[1];                                     \
    acc0.x = fmaf(HK, wa.x, acc0.x); acc0.y = fmaf(HK, wa.y, acc0.y);           \
    acc0.z = fmaf(HK, wa.z, acc0.z); acc0.w = fmaf(HK, wa.w, acc0.w);           \
    acc1.x = fmaf(HK, wb.x, acc1.x); acc1.y = fmaf(HK, wb.y, acc1.y);           \
    acc1.z = fmaf(HK, wb.z, acc1.z); acc1.w = fmaf(HK, wb.w, acc1.w);           \
} while (0)

// Fused gather+conv, 64 nodes/block, 512 threads (16 half-waves x 4 nodes).
__global__ __launch_bounds__(512, 6) void gconv(const unsigned* __restrict__ row_ptr,
                                                const int* __restrict__ csr_src,
                                                const unsigned* __restrict__ hn_in,
                                                const float* __restrict__ W,
                                                const float* __restrict__ b,
                                                const float* __restrict__ dinv,
                                                unsigned* __restrict__ hn_out, int N) {
    __shared__ float ybuf[64 * 65];   // [feature][node]
    __shared__ int eLDS[ECAP];
    int tid = threadIdx.x;
    int hw = tid >> 5, fl = tid & 31;
    int base = blockIdx.x * 64;
    int topN = min(base + 64, N);
    unsigned e0b = row_ptr[base];
    unsigned e1b = row_ptr[topN];
    int m = (int)(e1b - e0b);
    int mc = min(m, ECAP);
    for (int j = tid; j < mc; j += 512) eLDS[j] = csr_src[e0b + j];
    __syncthreads();
    for (int s = 0; s < 4; s++) {
        int n = hw * 4 + s;
        int i = base + n;
        if (i < N) {
            unsigned er0 = row_ptr[i];
            unsigned cnt = row_ptr[i + 1] - er0;
            int r0 = (int)(er0 - e0b);
            float2 a;
            if (r0 + (int)cnt <= mc)
                a = gather_row_lds(eLDS, r0, cnt, hn_in, i, fl);
            else
                a = gather_row(row_ptr, csr_src, hn_in, i, fl);
            ybuf[(2 * fl) * 65 + n] = a.x;
            ybuf[(2 * fl + 1) * 65 + n] = a.y;
        }
    }
    __syncthreads();
    int n = tid & 63;
    int qt = __builtin_amdgcn_readfirstlane(tid >> 6);   // 0..7, wave-uniform
    int i = base + n;
    if (i >= N) return;
    int jb = qt * 8;
    float di = dinv[i];
    float4 acc0 = {0.f, 0.f, 0.f, 0.f}, acc1 = acc0;
    const float* Wj = W + jb;
#pragma unroll
    for (int k = 0; k < 64; k++) {
        float hk = ybuf[k * 65 + n];
        CONV_K8(Wj + k * 64, hk);
    }
    const float* bj = b + jb;
    float4 y0, y1;
    y0.x = fmaxf(fmaf(di, acc0.x, bj[0]), 0.f) * di;
    y0.y = fmaxf(fmaf(di, acc0.y, bj[1]), 0.f) * di;
    y0.z = fmaxf(fmaf(di, acc0.z, bj[2]), 0.f) * di;
    y0.w = fmaxf(fmaf(di, acc0.w, bj[3]), 0.f) * di;
    y1.x = fmaxf(fmaf(di, acc1.x, bj[4]), 0.f) * di;
    y1.y = fmaxf(fmaf(di, acc1.y, bj[5]), 0.f) * di;
    y1.z = fmaxf(fmaf(di, acc1.z, bj[6]), 0.f) * di;
    y1.w = fmaxf(fmaf(di, acc1.w, bj[7]), 0.f) * di;
    uint4 p;
    p.x = bfpack(y0.x, y0.y);
    p.y = bfpack(y0.z, y0.w);
    p.z = bfpack(y1.x, y1.y);
    p.w = bfpack(y1.z, y1.w);
    *(uint4*)(hn_out + (size_t)i * 32 + qt * 4) = p;
}

// Layer 2: fused gather + conv + both MLP heads -> out (512 threads).
__global__ __launch_bounds__(512, 6) void gconv_heads(const unsigned* __restrict__ row_ptr,
                                                      const int* __restrict__ csr_src,
                                                      const unsigned* __restrict__ hn_in,
                                                      const float* __restrict__ W,
                                                      const float* __restrict__ b,
                                                      const float* __restrict__ dinv,
                                                      const float* __restrict__ W_d1, const float* __restrict__ b_d1,
                                                      const float* __restrict__ W_d2, const float* __restrict__ b_d2,
                                                      const float* __restrict__ W_i1, const float* __restrict__ b_i1,
                                                      const float* __restrict__ W_i2, const float* __restrict__ b_i2,
                                                      float* __restrict__ out, int N) {
    __shared__ float ybuf[64 * 65];   // gathered rows, later y rows (feature-major)
    __shared__ int eLDS[ECAP];
    __shared__ float opart[512];
    int tid = threadIdx.x;
    int hw = tid >> 5, fl = tid & 31;
    int base = blockIdx.x * 64;
    int topN = min(base + 64, N);
    unsigned e0b = row_ptr[base];
    unsigned e1b = row_ptr[topN];
    int m = (int)(e1b - e0b);
    int mc = min(m, ECAP);
    for (int j = tid; j < mc; j += 512) eLDS[j] = csr_src[e0b + j];
    __syncthreads();
    for (int s = 0; s < 4; s++) {
        int n = hw * 4 + s;
        int i = base + n;
        if (i < N) {
            unsigned er0 = row_ptr[i];
            unsigned cnt = row_ptr[i + 1] - er0;
            int r0 = (int)(er0 - e0b);
            float2 a;
            if (r0 + (int)cnt <= mc)
                a = gather_row_lds(eLDS, r0, cnt, hn_in, i, fl);
            else
                a = gather_row(row_ptr, csr_src, hn_in, i, fl);
            ybuf[(2 * fl) * 65 + n] = a.x;
            ybuf[(2 * fl + 1) * 65 + n] = a.y;
        }
    }
    __syncthreads();
    int n = tid & 63;
    int qt = __builtin_amdgcn_readfirstlane(tid >> 6);   // 0..7, wave-uniform
    int i = base + n;
    int jb = qt * 8;
    float y[8];
    if (i < N) {
        float di = dinv[i];
        float4 acc0 = {0.f, 0.f, 0.f, 0.f}, acc1 = acc0;
        const float* Wj = W + jb;
#pragma unroll
        for (int k = 0; k < 64; k++) {
            float hk = ybuf[k * 65 + n];
            CONV_K8(Wj + k * 64, hk);
        }
        const float* bj = b + jb;
        y[0] = fmaxf(fmaf(di, acc0.x, bj[0]), 0.f);
        y[1] = fmaxf(fmaf(di, acc0.y, bj[1]), 0.f);
        y[2] = fmaxf(fmaf(di, acc0.z, bj[2]), 0.f);
        y[3] = fmaxf(fmaf(di, acc0.w, bj[3]), 0.f);
        y[4] = fmaxf(fmaf(di, acc1.x, bj[4]), 0.f);
        y[5] = fmaxf(fmaf(di, acc1.y, bj[5]), 0.f);
        y[6] = fmaxf(fmaf(di, acc1.z, bj[6]), 0.f);
        y[7] = fmaxf(fmaf(di, acc1.w, bj[7]), 0.f);
    }
    __syncthreads();   // all conv reads of ybuf done
    if (i < N) {
#pragma unroll
        for (int jj = 0; jj < 8; jj++) ybuf[(jb + jj) * 65 + n] = y[jj];
    }
    __syncthreads();
    // heads: hd = tid>>8 (head), q2 = (tid>>6)&3 (8-out group), n = tid&63
    int hd = __builtin_amdgcn_readfirstlane(tid >> 8);        // 0/1, wave-uniform
    int q2 = __builtin_amdgcn_readfirstlane((tid >> 6) & 3);  // 0..3, wave-uniform
    int hb = q2 * 8;
    float op = 0.f;
    if (i < N) {
        const float* W1 = (hd ? W_i1 : W_d1) + hb;   // [64][32] row-major
        const float* b1 = (hd ? b_i1 : b_d1) + hb;
        const float* W2 = (hd ? W_i2 : W_d2) + hb;
        float4 acc0 = {0.f, 0.f, 0.f, 0.f}, acc1 = acc0;
#pragma unroll
        for (int k = 0; k < 64; k++) {
            float hk = ybuf[k * 65 + n];
            CONV_K8(W1 + k * 32, hk);
        }
        op = fmaf(fmaxf(acc0.x + b1[0], 0.f), W2[0], op);
        op = fmaf(fmaxf(acc0.y + b1[1], 0.f), W2[1], op);
        op = fmaf(fmaxf(acc0.z + b1[2], 0.f), W2[2], op);
        op = fmaf(fmaxf(acc0.w + b1[3], 0.f), W2[3], op);
        op = fmaf(fmaxf(acc1.x + b1[4], 0.f), W2[4], op);
        op = fmaf(fmaxf(acc1.y + b1[5], 0.f), W2[5], op);
        op = fmaf(fmaxf(acc1.z + b1[6], 0.f), W2[6], op);
        op = fmaf(fmaxf(acc1.w + b1[7], 0.f), W2[7], op);
    }
    opart[tid] = op;
    __syncthreads();
    if (tid < 128) {
        int n2 = tid & 63, h2 = tid >> 6;
        int i2 = base + n2;
        if (i2 < N) {
            int o0 = h2 * 256 + n2;
            float o = opart[o0] + opart[o0 + 64] + opart[o0 + 128] + opart[o0 + 192]
                    + (h2 ? b_i2[0] : b_d2[0]);
            out[(size_t)h2 * N + i2] = o;
        }
    }
}

extern "C" void kernel_launch(void* const* d_in, const int* in_sizes, int n_in,
                              void* d_out, int out_size, void* d_ws, size_t ws_size,
                              hipStream_t stream) {
    const float* x      = (const float*)d_in[0];
    const int*   ei     = (const int*)d_in[1];
    const float* W_enc  = (const float*)d_in[2];
    const float* b_enc  = (const float*)d_in[3];
    const float* conv_W = (const float*)d_in[4];
    const float* conv_b = (const float*)d_in[5];
    const float* W_d1   = (const float*)d_in[6];
    const float* b_d1   = (const float*)d_in[7];
    const float* W_d2   = (const float*)d_in[8];
    const float* b_d2   = (const float*)d_in[9];
    const float* W_i1   = (const float*)d_in[10];
    const float* b_i1   = (const float*)d_in[11];
    const float* W_i2   = (const float*)d_in[12];
    const float* b_i2   = (const float*)d_in[13];

    const int N = in_sizes[0] / 5;
    const int E = in_sizes[1] / 2;
    const int NB = (N + NPB - 1) >> NPB_SHIFT;   // <= 256

    // Workspace layout (same as R14; hnA aliases ebuf — ebuf dead before encoder).
    float* g    = (float*)d_ws;                           // [N*64] region
    unsigned* hnA = (unsigned*)d_ws;                      // [N*32] bf16x2
    unsigned* hnB = (unsigned*)(g + (size_t)N * HDIM);    // [N*32] bf16x2
    float* dinv = (float*)(hnB + (size_t)N * 32);
    unsigned* row_ptr = (unsigned*)(dinv + N);            // [N+1]
    unsigned* histT   = row_ptr + N + 1;                  // [NB*PB]
    unsigned* btot    = histT + (size_t)NB * PB;          // [NB]
    int* csr_src      = (int*)(btot + NB);                // [E]
    unsigned* ebuf    = (unsigned*)d_ws;                  // [E] packed (dead before encoder)
    float* out = (float*)d_out;

    const int gBlocks = (N + 63) / 64;   // 64 nodes per fused block

    // CSR build: bucket sort, no global atomics
    hist_pass<<<PB, 256, 0, stream>>>(ei + E, histT, E, NB);
    scan_bucket<<<NB, 128, 0, stream>>>(histT, btot);
    bin_pass<<<PB, 256, 0, stream>>>(ei, histT, btot, ebuf, E, NB);
    csr_pass<<<NB, 256, 0, stream>>>(ebuf, btot, row_ptr, dinv, csr_src, N, E, NB);

    // encoder -> hnA (bf16, dinv-prescaled)
    encoder<<<(N * 32 + 255) / 256, 256, 0, stream>>>(x, W_enc, b_enc, dinv, hnA, N);

    // fused gather+conv per layer (ping-pong hnA/hnB), layer 2 fused with heads
    gconv<<<gBlocks, 512, 0, stream>>>(row_ptr, csr_src, hnA,
                                       conv_W + 0 * HDIM * HDIM, conv_b + 0 * HDIM,
                                       dinv, hnB, N);
    gconv<<<gBlocks, 512, 0, stream>>>(row_ptr, csr_src, hnB,
                                       conv_W + 1 * HDIM * HDIM, conv_b + 1 * HDIM,
                                       dinv, hnA, N);
    gconv_heads<<<gBlocks, 512, 0, stream>>>(row_ptr, csr_src, hnA,
                                             conv_W + 2 * HDIM * HDIM, conv_b + 2 * HDIM,
                                             dinv, W_d1, b_d1, W_d2, b_d2,
                                             W_i1, b_i1, W_i2, b_i2, out, N);
}

// Round 5
// 223.187 us; speedup vs baseline: 1.0968x; 1.0968x over previous
//
#include <hip/hip_runtime.h>
#include <hip/hip_bf16.h>

// SupplyChainGNN: 3-layer GCN, N=50000, E=800000, H=64.
// Round 16: revert R15 (LDS-idx staging + 16-deep regressed: idx loads were
// already L1-resident; clamped-16 remainder added 10-15% requests). Base = R14.
// Change 1: gather by QUARTER-wave (16 lanes x uint2) -> same 128B/edge request,
// 2x independent latency chains per CU (~768 outstanding vs 384).
// Change 2: CSR build PB 128->256 (hist/bin were using half the CUs).

#define HDIM 64
#define PB 256          // blocks in hist/bin passes
#define NPB 256         // nodes per bucket
#define NPB_SHIFT 8

__device__ inline unsigned bfpack(float lo, float hi) {
    unsigned ul = __float_as_uint(lo), uh = __float_as_uint(hi);
    ul += 0x7fffu + ((ul >> 16) & 1u);
    uh += 0x7fffu + ((uh >> 16) & 1u);
    return (ul >> 16) | (uh & 0xffff0000u);
}

__device__ inline float2 bfunpack(unsigned u) {
    float2 r;
    r.x = __uint_as_float(u << 16);
    r.y = __uint_as_float(u & 0xffff0000u);
    return r;
}

// Pass 1: histT[k*PB + p] = #edges of block p with dst in bucket k  (NB<=256)
__global__ __launch_bounds__(256) void hist_pass(const int* __restrict__ dst,
                                                 unsigned* __restrict__ histT,
                                                 int E, int NB) {
    __shared__ unsigned h[256];
    int t = threadIdx.x, p = blockIdx.x;
    h[t] = 0u;
    __syncthreads();
    int chunk = (E + PB - 1) / PB;
    int lo = p * chunk, hi = min(lo + chunk, E);
    for (int e = lo + t; e < hi; e += 256)
        atomicAdd(&h[dst[e] >> NPB_SHIFT], 1u);
    __syncthreads();
    if (t < NB) histT[t * PB + p] = h[t];
}

// Pass 2: per-bucket exclusive scan of its PB per-block counts (in place);
// bucket total -> btot[k].
__global__ __launch_bounds__(PB) void scan_bucket(unsigned* __restrict__ histT,
                                                  unsigned* __restrict__ btot) {
    __shared__ unsigned s[PB];
    int t = threadIdx.x, k = blockIdx.x;
    unsigned v = histT[k * PB + t];
    s[t] = v;
    __syncthreads();
#pragma unroll
    for (int off = 1; off < PB; off <<= 1) {
        unsigned u = (t >= off) ? s[t - off] : 0u;
        __syncthreads();
        s[t] += u;
        __syncthreads();
    }
    histT[k * PB + t] = s[t] - v;
    if (t == PB - 1) btot[k] = s[t];
}

// Pass 3: scatter packed (dst_local<<16)|src into bucket-grouped ebuf.
__global__ __launch_bounds__(256) void bin_pass(const int* __restrict__ ei,
                                                const unsigned* __restrict__ histT,
                                                const unsigned* __restrict__ btot,
                                                unsigned* __restrict__ ebuf,
                                                int E, int NB) {
    __shared__ unsigned bb[256];
    __shared__ unsigned cur[256];
    int t = threadIdx.x, p = blockIdx.x;
    unsigned bv = (t < NB) ? btot[t] : 0u;
    bb[t] = bv;
    __syncthreads();
#pragma unroll
    for (int off = 1; off < 256; off <<= 1) {
        unsigned u = (t >= off) ? bb[t - off] : 0u;
        __syncthreads();
        bb[t] += u;
        __syncthreads();
    }
    if (t < NB) cur[t] = histT[t * PB + p] + (bb[t] - bv);
    __syncthreads();
    int chunk = (E + PB - 1) / PB;
    int lo = p * chunk, hi = min(lo + chunk, E);
    for (int e = lo + t; e < hi; e += 256) {
        unsigned sN = (unsigned)ei[e];
        unsigned dN = (unsigned)ei[E + e];
        unsigned pos = atomicAdd(&cur[dN >> NPB_SHIFT], 1u);
        ebuf[pos] = ((dN & (NPB - 1u)) << 16) | sN;
    }
}

// Pass 4: one block per bucket -> row_ptr, dinv, csr_src.
__global__ __launch_bounds__(256) void csr_pass(const unsigned* __restrict__ ebuf,
                                                const unsigned* __restrict__ btot,
                                                unsigned* __restrict__ row_ptr,
                                                float* __restrict__ dinv,
                                                int* __restrict__ csr_src,
                                                int N, int E, int NB) {
    __shared__ unsigned bb[256];
    __shared__ unsigned cntL[NPB];
    __shared__ unsigned sc[NPB];
    __shared__ unsigned cur[NPB];
    int t = threadIdx.x, k = blockIdx.x;
    unsigned bv = (t < NB) ? btot[t] : 0u;
    bb[t] = bv;
    __syncthreads();
#pragma unroll
    for (int off = 1; off < 256; off <<= 1) {
        unsigned u = (t >= off) ? bb[t - off] : 0u;
        __syncthreads();
        bb[t] += u;
        __syncthreads();
    }
    unsigned e1 = bb[k];
    unsigned e0 = e1 - btot[k];
    int nbase = k << NPB_SHIFT;
    cntL[t] = 0u;
    __syncthreads();
    for (unsigned e = e0 + t; e < e1; e += 256)
        atomicAdd(&cntL[ebuf[e] >> 16], 1u);
    __syncthreads();
    unsigned v = cntL[t];
    sc[t] = v;
    __syncthreads();
#pragma unroll
    for (int off = 1; off < NPB; off <<= 1) {
        unsigned u = (t >= off) ? sc[t - off] : 0u;
        __syncthreads();
        sc[t] += u;
        __syncthreads();
    }
    unsigned pos0 = e0 + sc[t] - v;
    cur[t] = pos0;
    int node = nbase + t;
    if (node < N) {
        row_ptr[node] = pos0;
        dinv[node] = rsqrtf((float)(v + 1u));
    }
    if (k == NB - 1 && t == 0) row_ptr[N] = (unsigned)E;
    __syncthreads();
    for (unsigned e = e0 + t; e < e1; e += 256) {
        unsigned ed = ebuf[e];
        unsigned pos = atomicAdd(&cur[ed >> 16], 1u);
        csr_src[pos] = (int)(ed & 0xffffu);
    }
}

// hn[i] = bf16( dinv[i] * relu(x@W+b) ); thread per feature-pair.
__global__ __launch_bounds__(256) void encoder(const float* __restrict__ x,
                                               const float* __restrict__ W,
                                               const float* __restrict__ b,
                                               const float* __restrict__ dinv,
                                               unsigned* __restrict__ hn, int N) {
    int t = blockIdx.x * 256 + threadIdx.x;
    int i = t >> 5, jp = t & 31;
    if (i >= N) return;
    int j0 = 2 * jp;
    float a0 = b[j0], a1 = b[j0 + 1];
#pragma unroll
    for (int k = 0; k < 5; k++) {
        float xv = x[i * 5 + k];
        a0 = fmaf(xv, W[k * 64 + j0], a0);
        a1 = fmaf(xv, W[k * 64 + j0 + 1], a1);
    }
    float di = dinv[i];
    hn[t] = bfpack(di * fmaxf(a0, 0.0f), di * fmaxf(a1, 0.0f));
}

#define ACC4(A, V) do {                                                         \
    float2 _p = bfunpack((V).x), _q = bfunpack((V).y);                          \
    (A).x += _p.x; (A).y += _p.y; (A).z += _q.x; (A).w += _q.y;                 \
} while (0)

#define MACC4(A, V, C) do {                                                     \
    float2 _p = bfunpack((V).x), _q = bfunpack((V).y);                          \
    (A).x += (C) ? _p.x : 0.f; (A).y += (C) ? _p.y : 0.f;                       \
    (A).z += (C) ? _q.x : 0.f; (A).w += (C) ? _q.y : 0.f;                       \
} while (0)

// Per-node gather by QUARTER-wave (16 lanes; lane fl owns features 4fl..4fl+3,
// one uint2 = 8B per lane -> 128B/edge, same line-request count as half-wave).
// 8-deep software pipeline; remainder clamped to last (same-line MSHR merge).
__device__ inline float4 gather_row_q(const unsigned* __restrict__ row_ptr,
                                      const int* __restrict__ csr_src,
                                      const uint2* __restrict__ hp,
                                      int i, int fl) {
    uint2 sv = hp[(size_t)i * 16 + fl];   // self term
    float4 a0, a1 = {0.f, 0.f, 0.f, 0.f}, a2 = a1, a3 = a1;
    {
        float2 p = bfunpack(sv.x), q = bfunpack(sv.y);
        a0.x = p.x; a0.y = p.y; a0.z = q.x; a0.w = q.y;
    }
    unsigned e0 = row_ptr[i];
    unsigned cnt = row_ptr[i + 1] - e0;
    const int* idx = csr_src + e0;
    unsigned u = 0;
    if (cnt >= 8) {
        int s0 = idx[0], s1 = idx[1], s2 = idx[2], s3 = idx[3];
        int s4 = idx[4], s5 = idx[5], s6 = idx[6], s7 = idx[7];
        while (true) {
            uint2 v0 = hp[(size_t)s0 * 16 + fl];
            uint2 v1 = hp[(size_t)s1 * 16 + fl];
            uint2 v2 = hp[(size_t)s2 * 16 + fl];
            uint2 v3 = hp[(size_t)s3 * 16 + fl];
            uint2 v4 = hp[(size_t)s4 * 16 + fl];
            uint2 v5 = hp[(size_t)s5 * 16 + fl];
            uint2 v6 = hp[(size_t)s6 * 16 + fl];
            uint2 v7 = hp[(size_t)s7 * 16 + fl];
            unsigned un = u + 8;
            bool more = (un + 8 <= cnt);
            if (more) {
                s0 = idx[un + 0]; s1 = idx[un + 1]; s2 = idx[un + 2]; s3 = idx[un + 3];
                s4 = idx[un + 4]; s5 = idx[un + 5]; s6 = idx[un + 6]; s7 = idx[un + 7];
            }
            ACC4(a0, v0); ACC4(a1, v1); ACC4(a2, v2); ACC4(a3, v3);
            ACC4(a0, v4); ACC4(a1, v5); ACC4(a2, v6); ACC4(a3, v7);
            u = un;
            if (!more) break;
        }
    }
    if (u < cnt) {  // predicated parallel remainder (1..7 edges)
        unsigned last = cnt - 1;
        int t0 = idx[u];
        int t1 = idx[min(u + 1, last)];
        int t2 = idx[min(u + 2, last)];
        int t3 = idx[min(u + 3, last)];
        int t4 = idx[min(u + 4, last)];
        int t5 = idx[min(u + 5, last)];
        int t6 = idx[min(u + 6, last)];
        int t7 = idx[min(u + 7, last)];
        uint2 w0 = hp[(size_t)t0 * 16 + fl];
        uint2 w1 = hp[(size_t)t1 * 16 + fl];
        uint2 w2 = hp[(size_t)t2 * 16 + fl];
        uint2 w3 = hp[(size_t)t3 * 16 + fl];
        uint2 w4 = hp[(size_t)t4 * 16 + fl];
        uint2 w5 = hp[(size_t)t5 * 16 + fl];
        uint2 w6 = hp[(size_t)t6 * 16 + fl];
        uint2 w7 = hp[(size_t)t7 * 16 + fl];
        ACC4(a0, w0);
        MACC4(a1, w1, u + 1 < cnt);
        MACC4(a2, w2, u + 2 < cnt);
        MACC4(a3, w3, u + 3 < cnt);
        MACC4(a0, w4, u + 4 < cnt);
        MACC4(a1, w5, u + 5 < cnt);
        MACC4(a2, w6, u + 6 < cnt);
        MACC4(a3, w7, u + 7 < cnt);
    }
    a0.x += a1.x; a0.y += a1.y; a0.z += a1.z; a0.w += a1.w;
    a2.x += a3.x; a2.y += a3.y; a2.z += a3.z; a2.w += a3.w;
    a0.x += a2.x; a0.y += a2.y; a0.z += a2.z; a0.w += a2.w;
    return a0;
}

// 8 FMAs: acc0,acc1 (float4) += hk * 8-wide W row segment (wave-uniform)
#define CONV_K8(WROW, HK) do {                                                  \
    float4 wa = ((const float4*)(WROW))[0];                                     \
    float4 wb = ((const float4*)(WROW))[1];                                     \
    acc0.x = fmaf(HK, wa.x, acc0.x); acc0.y = fmaf(HK, wa.y, acc0.y);           \
    acc0.z = fmaf(HK, wa.z, acc0.z); acc0.w = fmaf(HK, wa.w, acc0.w);           \
    acc1.x = fmaf(HK, wb.x, acc1.x); acc1.y = fmaf(HK, wb.y, acc1.y);           \
    acc1.z = fmaf(HK, wb.z, acc1.z); acc1.w = fmaf(HK, wb.w, acc1.w);           \
} while (0)

// Fused gather+conv, 64 nodes/block, 512 threads (32 quarter-waves x 2 nodes).
// Conv: thread per (node n=tid&63, 8 outputs jb=(tid>>6)*8); W rows via
// wave-uniform scalar loads.
__global__ __launch_bounds__(512, 6) void gconv(const unsigned* __restrict__ row_ptr,
                                                const int* __restrict__ csr_src,
                                                const unsigned* __restrict__ hn_in,
                                                const float* __restrict__ W,
                                                const float* __restrict__ b,
                                                const float* __restrict__ dinv,
                                                unsigned* __restrict__ hn_out, int N) {
    __shared__ float ybuf[64 * 65];   // [feature][node]
    int tid = threadIdx.x;
    int qw = tid >> 4, fl = tid & 15;
    int base = blockIdx.x * 64;
    for (int s = 0; s < 2; s++) {
        int n = qw * 2 + s;
        int i = base + n;
        if (i < N) {
            float4 a = gather_row_q(row_ptr, csr_src, (const uint2*)hn_in, i, fl);
            ybuf[(4 * fl + 0) * 65 + n] = a.x;
            ybuf[(4 * fl + 1) * 65 + n] = a.y;
            ybuf[(4 * fl + 2) * 65 + n] = a.z;
            ybuf[(4 * fl + 3) * 65 + n] = a.w;
        }
    }
    __syncthreads();
    int n = tid & 63;
    int qt = __builtin_amdgcn_readfirstlane(tid >> 6);   // 0..7, wave-uniform
    int i = base + n;
    if (i >= N) return;
    int jb = qt * 8;
    float di = dinv[i];
    float4 acc0 = {0.f, 0.f, 0.f, 0.f}, acc1 = acc0;
    const float* Wj = W + jb;
#pragma unroll
    for (int k = 0; k < 64; k++) {
        float hk = ybuf[k * 65 + n];
        CONV_K8(Wj + k * 64, hk);
    }
    const float* bj = b + jb;
    float4 y0, y1;
    y0.x = fmaxf(fmaf(di, acc0.x, bj[0]), 0.f) * di;
    y0.y = fmaxf(fmaf(di, acc0.y, bj[1]), 0.f) * di;
    y0.z = fmaxf(fmaf(di, acc0.z, bj[2]), 0.f) * di;
    y0.w = fmaxf(fmaf(di, acc0.w, bj[3]), 0.f) * di;
    y1.x = fmaxf(fmaf(di, acc1.x, bj[4]), 0.f) * di;
    y1.y = fmaxf(fmaf(di, acc1.y, bj[5]), 0.f) * di;
    y1.z = fmaxf(fmaf(di, acc1.z, bj[6]), 0.f) * di;
    y1.w = fmaxf(fmaf(di, acc1.w, bj[7]), 0.f) * di;
    uint4 p;
    p.x = bfpack(y0.x, y0.y);
    p.y = bfpack(y0.z, y0.w);
    p.z = bfpack(y1.x, y1.y);
    p.w = bfpack(y1.z, y1.w);
    *(uint4*)(hn_out + (size_t)i * 32 + qt * 4) = p;
}

// Layer 2: fused gather + conv + both MLP heads -> out (512 threads).
__global__ __launch_bounds__(512, 6) void gconv_heads(const unsigned* __restrict__ row_ptr,
                                                      const int* __restrict__ csr_src,
                                                      const unsigned* __restrict__ hn_in,
                                                      const float* __restrict__ W,
                                                      const float* __restrict__ b,
                                                      const float* __restrict__ dinv,
                                                      const float* __restrict__ W_d1, const float* __restrict__ b_d1,
                                                      const float* __restrict__ W_d2, const float* __restrict__ b_d2,
                                                      const float* __restrict__ W_i1, const float* __restrict__ b_i1,
                                                      const float* __restrict__ W_i2, const float* __restrict__ b_i2,
                                                      float* __restrict__ out, int N) {
    __shared__ float ybuf[64 * 65];   // gathered rows, later y rows (feature-major)
    __shared__ float opart[512];
    int tid = threadIdx.x;
    int qw = tid >> 4, fl = tid & 15;
    int base = blockIdx.x * 64;
    for (int s = 0; s < 2; s++) {
        int n = qw * 2 + s;
        int i = base + n;
        if (i < N) {
            float4 a = gather_row_q(row_ptr, csr_src, (const uint2*)hn_in, i, fl);
            ybuf[(4 * fl + 0) * 65 + n] = a.x;
            ybuf[(4 * fl + 1) * 65 + n] = a.y;
            ybuf[(4 * fl + 2) * 65 + n] = a.z;
            ybuf[(4 * fl + 3) * 65 + n] = a.w;
        }
    }
    __syncthreads();
    int n = tid & 63;
    int qt = __builtin_amdgcn_readfirstlane(tid >> 6);   // 0..7, wave-uniform
    int i = base + n;
    int jb = qt * 8;
    float y[8];
    if (i < N) {
        float di = dinv[i];
        float4 acc0 = {0.f, 0.f, 0.f, 0.f}, acc1 = acc0;
        const float* Wj = W + jb;
#pragma unroll
        for (int k = 0; k < 64; k++) {
            float hk = ybuf[k * 65 + n];
            CONV_K8(Wj + k * 64, hk);
        }
        const float* bj = b + jb;
        y[0] = fmaxf(fmaf(di, acc0.x, bj[0]), 0.f);
        y[1] = fmaxf(fmaf(di, acc0.y, bj[1]), 0.f);
        y[2] = fmaxf(fmaf(di, acc0.z, bj[2]), 0.f);
        y[3] = fmaxf(fmaf(di, acc0.w, bj[3]), 0.f);
        y[4] = fmaxf(fmaf(di, acc1.x, bj[4]), 0.f);
        y[5] = fmaxf(fmaf(di, acc1.y, bj[5]), 0.f);
        y[6] = fmaxf(fmaf(di, acc1.z, bj[6]), 0.f);
        y[7] = fmaxf(fmaf(di, acc1.w, bj[7]), 0.f);
    }
    __syncthreads();   // all conv reads of ybuf done
    if (i < N) {
#pragma unroll
        for (int jj = 0; jj < 8; jj++) ybuf[(jb + jj) * 65 + n] = y[jj];
    }
    __syncthreads();
    // heads: hd = tid>>8 (head), q2 = (tid>>6)&3 (8-out group), n = tid&63
    int hd = __builtin_amdgcn_readfirstlane(tid >> 8);        // 0/1, wave-uniform
    int q2 = __builtin_amdgcn_readfirstlane((tid >> 6) & 3);  // 0..3, wave-uniform
    int hb = q2 * 8;
    float op = 0.f;
    if (i < N) {
        const float* W1 = (hd ? W_i1 : W_d1) + hb;   // [64][32] row-major
        const float* b1 = (hd ? b_i1 : b_d1) + hb;
        const float* W2 = (hd ? W_i2 : W_d2) + hb;
        float4 acc0 = {0.f, 0.f, 0.f, 0.f}, acc1 = acc0;
#pragma unroll
        for (int k = 0; k < 64; k++) {
            float hk = ybuf[k * 65 + n];
            CONV_K8(W1 + k * 32, hk);
        }
        op = fmaf(fmaxf(acc0.x + b1[0], 0.f), W2[0], op);
        op = fmaf(fmaxf(acc0.y + b1[1], 0.f), W2[1], op);
        op = fmaf(fmaxf(acc0.z + b1[2], 0.f), W2[2], op);
        op = fmaf(fmaxf(acc0.w + b1[3], 0.f), W2[3], op);
        op = fmaf(fmaxf(acc1.x + b1[4], 0.f), W2[4], op);
        op = fmaf(fmaxf(acc1.y + b1[5], 0.f), W2[5], op);
        op = fmaf(fmaxf(acc1.z + b1[6], 0.f), W2[6], op);
        op = fmaf(fmaxf(acc1.w + b1[7], 0.f), W2[7], op);
    }
    opart[tid] = op;
    __syncthreads();
    if (tid < 128) {
        int n2 = tid & 63, h2 = tid >> 6;
        int i2 = base + n2;
        if (i2 < N) {
            int o0 = h2 * 256 + n2;
            float o = opart[o0] + opart[o0 + 64] + opart[o0 + 128] + opart[o0 + 192]
                    + (h2 ? b_i2[0] : b_d2[0]);
            out[(size_t)h2 * N + i2] = o;
        }
    }
}

extern "C" void kernel_launch(void* const* d_in, const int* in_sizes, int n_in,
                              void* d_out, int out_size, void* d_ws, size_t ws_size,
                              hipStream_t stream) {
    const float* x      = (const float*)d_in[0];
    const int*   ei     = (const int*)d_in[1];
    const float* W_enc  = (const float*)d_in[2];
    const float* b_enc  = (const float*)d_in[3];
    const float* conv_W = (const float*)d_in[4];
    const float* conv_b = (const float*)d_in[5];
    const float* W_d1   = (const float*)d_in[6];
    const float* b_d1   = (const float*)d_in[7];
    const float* W_d2   = (const float*)d_in[8];
    const float* b_d2   = (const float*)d_in[9];
    const float* W_i1   = (const float*)d_in[10];
    const float* b_i1   = (const float*)d_in[11];
    const float* W_i2   = (const float*)d_in[12];
    const float* b_i2   = (const float*)d_in[13];

    const int N = in_sizes[0] / 5;
    const int E = in_sizes[1] / 2;
    const int NB = (N + NPB - 1) >> NPB_SHIFT;   // <= 256

    // Workspace layout (same as R14; hnA aliases ebuf — ebuf dead before encoder).
    float* g    = (float*)d_ws;                           // [N*64] region
    unsigned* hnA = (unsigned*)d_ws;                      // [N*32] bf16x2
    unsigned* hnB = (unsigned*)(g + (size_t)N * HDIM);    // [N*32] bf16x2
    float* dinv = (float*)(hnB + (size_t)N * 32);
    unsigned* row_ptr = (unsigned*)(dinv + N);            // [N+1]
    unsigned* histT   = row_ptr + N + 1;                  // [NB*PB]
    unsigned* btot    = histT + (size_t)NB * PB;          // [NB]
    int* csr_src      = (int*)(btot + NB);                // [E]
    unsigned* ebuf    = (unsigned*)d_ws;                  // [E] packed (dead before encoder)
    float* out = (float*)d_out;

    const int gBlocks = (N + 63) / 64;   // 64 nodes per fused block

    // CSR build: bucket sort, no global atomics
    hist_pass<<<PB, 256, 0, stream>>>(ei + E, histT, E, NB);
    scan_bucket<<<NB, PB, 0, stream>>>(histT, btot);
    bin_pass<<<PB, 256, 0, stream>>>(ei, histT, btot, ebuf, E, NB);
    csr_pass<<<NB, 256, 0, stream>>>(ebuf, btot, row_ptr, dinv, csr_src, N, E, NB);

    // encoder -> hnA (bf16, dinv-prescaled)
    encoder<<<(N * 32 + 255) / 256, 256, 0, stream>>>(x, W_enc, b_enc, dinv, hnA, N);

    // fused gather+conv per layer (ping-pong hnA/hnB), layer 2 fused with heads
    gconv<<<gBlocks, 512, 0, stream>>>(row_ptr, csr_src, hnA,
                                       conv_W + 0 * HDIM * HDIM, conv_b + 0 * HDIM,
                                       dinv, hnB, N);
    gconv<<<gBlocks, 512, 0, stream>>>(row_ptr, csr_src, hnB,
                                       conv_W + 1 * HDIM * HDIM, conv_b + 1 * HDIM,
                                       dinv, hnA, N);
    gconv_heads<<<gBlocks, 512, 0, stream>>>(row_ptr, csr_src, hnA,
                                             conv_W + 2 * HDIM * HDIM, conv_b + 2 * HDIM,
                                             dinv, W_d1, b_d1, W_d2, b_d2,
                                             W_i1, b_i1, W_i2, b_i2, out, N);
}